// Round 12
// baseline (168.548 us; speedup 1.0000x reference)
//
#include <hip/hip_runtime.h>
#include <cstddef>
#include <cstdint>

#define BB 8
#define SS 256
#define EE 256
#define NN1 16
#define NN2 16
#define DD 100
#define QQ 768

__device__ __forceinline__ float dot4(float4 a, float4 b) {
    return a.x * b.x + a.y * b.y + a.z * b.z + a.w * b.w;
}

#define LGKM0() do { asm volatile("s_waitcnt lgkmcnt(0)" ::: "memory"); \
                     __builtin_amdgcn_sched_barrier(0); } while (0)
#define SCHED0() __builtin_amdgcn_sched_barrier(0)

// ---------------------------------------------------------------------------
// prep: blocks 0..15 -> per (b, layer) compute qk = 0.1 * Wk^T tanh(Wq q0 + bq)
//       blocks 16..23 -> per b inclusive scan of (input_ent != 0) -> rank (-1 = masked)
// ---------------------------------------------------------------------------
__global__ __launch_bounds__(256) void prep_kernel(
    const float* __restrict__ q, const int* __restrict__ ent,
    const float* __restrict__ Wq2, const float* __restrict__ bq2, const float* __restrict__ Wk2,
    const float* __restrict__ Wq1, const float* __restrict__ bq1, const float* __restrict__ Wk1,
    float* __restrict__ qk2o, float* __restrict__ qk1o, int* __restrict__ rk)
{
    const int blk = blockIdx.x, t = threadIdx.x;
    if (blk < 16) {
        const int b = blk >> 1, layer = blk & 1;
        const float* Wq = layer ? Wq1 : Wq2;
        const float* bq = layer ? bq1 : bq2;
        const float* Wk = layer ? Wk1 : Wk2;
        float* qko      = layer ? qk1o : qk2o;
        __shared__ float s_q[QQ];
        __shared__ float s_qi[DD];
        for (int i = t; i < QQ; i += 256) s_q[i] = q[(size_t)b * SS * QQ + i]; // q[b,0,:]
        __syncthreads();
        const float4* sq4 = (const float4*)s_q;
        const int r = t & 7;
        for (int d = t >> 3; d < DD; d += 32) {
            const float4* wq4 = (const float4*)(Wq + (size_t)d * QQ);
            float acc = 0.f;
            for (int c = r; c < QQ / 4; c += 8) acc += dot4(wq4[c], sq4[c]);
            acc += __shfl_xor(acc, 1, 8);
            acc += __shfl_xor(acc, 2, 8);
            acc += __shfl_xor(acc, 4, 8);
            if (r == 0) s_qi[d] = tanhf(acc + bq[d]);
        }
        __syncthreads();
        if (t < DD) {
            float acc = 0.f;
            for (int d = 0; d < DD; ++d) acc += s_qi[d] * Wk[d * DD + t]; // (Wk^T q_i)[t]
            qko[b * DD + t] = 0.1f * acc;   // fold 1/sqrt(100)
        }
    } else {
        const int b = blk - 16;
        __shared__ int s_m[SS];
        const int m = (ent[b * SS + t] != 0) ? 1 : 0;
        s_m[t] = m;
        __syncthreads();
        for (int off = 1; off < SS; off <<= 1) {
            const int add = (t >= off) ? s_m[t - off] : 0;
            __syncthreads();
            s_m[t] += add;
            __syncthreads();
        }
        int rank = s_m[t] - 1;
        rank = rank < 0 ? 0 : (rank > EE - 1 ? EE - 1 : rank);
        rk[b * SS + t] = m ? rank : -1;
    }
}

// ---------------------------------------------------------------------------
// dk2: single-wave blocks, 4-slot LDS ring filled by global_load_lds DMA
// (no VGPR staging -> compiler cannot sink the prefetch). Each unit =
// 14 DMA instructions (K 6.4 KB + V 6.4 KB, 1 KB each, overlap tail).
// Steady state: 3 future units (~38 KB) always in flight; waits are counted
// vmcnt, never 0 until the epilogue. Compute is wave-internal (no barriers):
// per-row dot from LDS, shfl softmax, PV from LDS, 2 scalar stores.
// ---------------------------------------------------------------------------
__global__ __launch_bounds__(64) void dk2_kernel(
    const float* __restrict__ k2, const float* __restrict__ v2,
    const float* __restrict__ qk2g, float* __restrict__ c2o,
    int b0, int nunits)
{
    const int t = threadIdx.x;
    const int r = t & 15, g = t >> 4;
    __shared__ float ring[4 * 3200];          // slot: K[1600] | V[1600]

    const int UPB = 64;
    const int u0 = blockIdx.x * UPB;
    if (u0 >= nunits) return;
    const int b = b0 + (u0 >> 12);            // 4096 units per batch; block never spans b

    // qk fragments for this lane (d = r + 16j)
    const float* qk = qk2g + (size_t)b * DD;
    float qj[6];
    #pragma unroll
    for (int j = 0; j < 6; ++j) qj[j] = qk[r + 16 * j];
    const float q6 = (r < 4) ? qk[96 + r] : 0.f;   // d = 96+r valid only r<4

    const char* kgl = (const char*)(k2 + ((size_t)b0 * 4096 + u0) * 1600);
    const char* vgl = (const char*)(v2 + ((size_t)b0 * 4096 + u0) * 1600);
    auto g1k = (const __attribute__((address_space(1))) char*)kgl;
    auto g1v = (const __attribute__((address_space(1))) char*)vgl;
    auto l3  = (__attribute__((address_space(3))) char*)ring;

    // one unit -> slot: 7 DMA for K + 7 for V. offsets 0..5*1024, tail 5376
    // (tail overlaps prior 768 B with identical data -> order-independent).
#define ISSUE_UNIT(rel, slot) do {                                              \
        const size_t gb_ = (size_t)(rel) * 6400;                                \
        const int    lb_ = (slot) * 12800;                                      \
        _Pragma("unroll")                                                       \
        for (int j_ = 0; j_ < 6; ++j_) {                                        \
            __builtin_amdgcn_global_load_lds(                                   \
                (const __attribute__((address_space(1))) void*)(g1k + gb_ + j_ * 1024 + t * 16), \
                (__attribute__((address_space(3))) void*)(l3 + lb_ + j_ * 1024), 16, 0, 0); \
        }                                                                       \
        __builtin_amdgcn_global_load_lds(                                       \
            (const __attribute__((address_space(1))) void*)(g1k + gb_ + 5376 + t * 16), \
            (__attribute__((address_space(3))) void*)(l3 + lb_ + 5376), 16, 0, 0); \
        _Pragma("unroll")                                                       \
        for (int j_ = 0; j_ < 6; ++j_) {                                        \
            __builtin_amdgcn_global_load_lds(                                   \
                (const __attribute__((address_space(1))) void*)(g1v + gb_ + j_ * 1024 + t * 16), \
                (__attribute__((address_space(3))) void*)(l3 + lb_ + 6400 + j_ * 1024), 16, 0, 0); \
        }                                                                       \
        __builtin_amdgcn_global_load_lds(                                       \
            (const __attribute__((address_space(1))) void*)(g1v + gb_ + 5376 + t * 16), \
            (__attribute__((address_space(3))) void*)(l3 + lb_ + 6400 + 5376), 16, 0, 0); \
    } while (0)

#define COMPUTE_STORE(uu) do {                                                  \
        const int   slot_ = (uu) & 3;                                           \
        const float* Ks_ = ring + slot_ * 3200;                                 \
        const float* Vs_ = Ks_ + 1600;                                          \
        float lgv[4];                                                           \
        _Pragma("unroll")                                                       \
        for (int i_ = 0; i_ < 4; ++i_) {                                        \
            const float* kr_ = Ks_ + (4 * g + i_) * DD;                         \
            float s_ = kr_[r] * qj[0];                                          \
            s_ += kr_[r + 16] * qj[1];                                          \
            s_ += kr_[r + 32] * qj[2];                                          \
            s_ += kr_[r + 48] * qj[3];                                          \
            s_ += kr_[r + 64] * qj[4];                                          \
            s_ += kr_[r + 80] * qj[5];                                          \
            s_ += kr_[96 + r] * q6;       /* q6==0 for r>=4: value irrelevant */\
            s_ += __shfl_xor(s_, 1, 16);                                        \
            s_ += __shfl_xor(s_, 2, 16);                                        \
            s_ += __shfl_xor(s_, 4, 16);                                        \
            s_ += __shfl_xor(s_, 8, 16);                                        \
            if (s_ == 0.0f) s_ = -10000.0f;                                     \
            lgv[i_] = s_ >= 0.f ? s_ : 0.01f * s_;         /* leaky_relu */     \
        }                                                                       \
        float m_ = fmaxf(fmaxf(lgv[0], lgv[1]), fmaxf(lgv[2], lgv[3]));         \
        m_ = fmaxf(m_, __shfl_xor(m_, 16, 64));                                 \
        m_ = fmaxf(m_, __shfl_xor(m_, 32, 64));                                 \
        const float e0_ = __expf(lgv[0] - m_), e1_ = __expf(lgv[1] - m_);       \
        const float e2_ = __expf(lgv[2] - m_), e3_ = __expf(lgv[3] - m_);       \
        float sm_ = e0_ + e1_ + e2_ + e3_;                                      \
        sm_ += __shfl_xor(sm_, 16, 64);                                         \
        sm_ += __shfl_xor(sm_, 32, 64);                                         \
        float p0_ = e0_ / sm_; if (p0_ == 0.0625f) p0_ = 0.f;                   \
        float p1_ = e1_ / sm_; if (p1_ == 0.0625f) p1_ = 0.f;                   \
        float p2_ = e2_ / sm_; if (p2_ == 0.0625f) p2_ = 0.f;                   \
        float p3_ = e3_ / sm_; if (p3_ == 0.0625f) p3_ = 0.f;                   \
        float a0_ = 0.f, a1_ = 0.f;                                             \
        _Pragma("unroll")                                                       \
        for (int n_ = 0; n_ < 16; ++n_) {                                       \
            float ps_;                                                          \
            switch (n_ & 3) {                                                   \
                case 0: ps_ = p0_; break;                                       \
                case 1: ps_ = p1_; break;                                       \
                case 2: ps_ = p2_; break;                                       \
                default: ps_ = p3_; break;                                      \
            }                                                                   \
            const float pn_ = __shfl(ps_, (n_ >> 2) * 16, 64);                  \
            a0_ += pn_ * Vs_[n_ * DD + t];                                      \
            a1_ += pn_ * Vs_[n_ * DD + 64 + t];  /* junk for t>=36, discarded */\
        }                                                                       \
        float* o_ = c2o + (size_t)(u0 + (uu)) * DD;                             \
        o_[t] = a0_;                                                            \
        if (t < 36) o_[64 + t] = a1_;                                           \
    } while (0)

    // prologue: fill 4 slots (56 DMA ops, ~51 KB in flight)
    ISSUE_UNIT(0, 0); ISSUE_UNIT(1, 1); ISSUE_UNIT(2, 2); ISSUE_UNIT(3, 3);

    int u = 0;
    for (; u < UPB - 4; ++u) {
        asm volatile("s_waitcnt vmcnt(42)" ::: "memory");  // unit u landed; 3 units + stores still in flight
        SCHED0();
        COMPUTE_STORE(u);
        SCHED0();
        ISSUE_UNIT(u + 4, u & 3);            // refill the slot just consumed
    }
    // epilogue: nothing left to issue; counted drains 42 -> 28 -> 14 -> 0
    asm volatile("s_waitcnt vmcnt(42)" ::: "memory"); SCHED0(); COMPUTE_STORE(UPB - 4);
    asm volatile("s_waitcnt vmcnt(28)" ::: "memory"); SCHED0(); COMPUTE_STORE(UPB - 3);
    asm volatile("s_waitcnt vmcnt(14)" ::: "memory"); SCHED0(); COMPUTE_STORE(UPB - 2);
    asm volatile("s_waitcnt vmcnt(0)"  ::: "memory"); SCHED0(); COMPUTE_STORE(UPB - 1);

#undef ISSUE_UNIT
#undef COMPUTE_STORE
}

// ---------------------------------------------------------------------------
// dk1: single-wave blocks, 2 per (bb,e): half 0 emits v1 part (d 0..99),
// half 1 emits c2 part (d 100..199). lgkmcnt-only syncs (1 wave).
// ---------------------------------------------------------------------------
__global__ __launch_bounds__(64) void dk1_kernel(
    const float* __restrict__ k1, const float* __restrict__ v1,
    const float* __restrict__ c2i, const float* __restrict__ qk1g,
    float* __restrict__ comb, int b0)
{
    const int blk  = blockIdx.x;
    const int bbe  = blk >> 1;           // chunk-local (bb,e)
    const int half = blk & 1;
    const int b    = b0 + (bbe >> 8);
    const int be   = (b << 8) | (bbe & 255);
    const int t    = threadIdx.x;

    __shared__ float4 s_pp[400];
    float* s_part = (float*)s_pp;

    const float4* kt = (const float4*)k1 + (size_t)be * 400;
    const float4* vt = half ? (const float4*)c2i + (size_t)bbe * 400
                            : (const float4*)v1 + (size_t)be * 400;
    const float4* qkb = (const float4*)qk1g + (size_t)b * 25;

    float4 qv[7];
    #pragma unroll
    for (int j = 0; j < 6; ++j) qv[j] = qkb[(t + 64 * j) % 25];
    qv[6] = qkb[(384 + t) % 25];

    float4 ka[7], va[7];
    #pragma unroll
    for (int j = 0; j < 6; ++j) { ka[j] = kt[t + 64 * j]; va[j] = vt[t + 64 * j]; }
    if (t < 16) { ka[6] = kt[384 + t]; va[6] = vt[384 + t]; }

    #pragma unroll
    for (int j = 0; j < 6; ++j) s_part[t + 64 * j] = dot4(ka[j], qv[j]);
    if (t < 16) s_part[384 + t] = dot4(ka[6], qv[6]);
    LGKM0();

    float p;
    {
        float lg = 0.f;
        if (t < 16) {
            #pragma unroll
            for (int c = 0; c < 25; ++c) lg += s_part[t * 25 + c];
            if (lg == 0.0f) lg = -10000.0f;
            lg = lg >= 0.f ? lg : 0.01f * lg;
        }
        float mx = lg;
        mx = fmaxf(mx, __shfl_xor(mx, 1, 16));
        mx = fmaxf(mx, __shfl_xor(mx, 2, 16));
        mx = fmaxf(mx, __shfl_xor(mx, 4, 16));
        mx = fmaxf(mx, __shfl_xor(mx, 8, 16));
        const float e = __expf(lg - mx);
        float sm = e;
        sm += __shfl_xor(sm, 1, 16);
        sm += __shfl_xor(sm, 2, 16);
        sm += __shfl_xor(sm, 4, 16);
        sm += __shfl_xor(sm, 8, 16);
        p = e / sm;
        if (p == 0.0625f) p = 0.f;
    }

    #pragma unroll
    for (int j = 0; j < 6; ++j) {
        const int i = t + 64 * j;
        const float pn = __shfl(p, i / 25, 64);
        s_pp[i] = make_float4(pn * va[j].x, pn * va[j].y, pn * va[j].z, pn * va[j].w);
    }
    if (t < 16) {
        const int i = 384 + t;
        const float pn = __shfl(p, 15, 64);
        s_pp[i] = make_float4(pn * va[6].x, pn * va[6].y, pn * va[6].z, pn * va[6].w);
    }
    LGKM0();

    if (t < 25) {
        float4 a = make_float4(0.f, 0.f, 0.f, 0.f);
        #pragma unroll
        for (int n = 0; n < 16; ++n) {
            const float4 x = s_pp[n * 25 + t];
            a.x += x.x; a.y += x.y; a.z += x.z; a.w += x.w;
        }
        ((float4*)comb)[(size_t)be * 50 + half * 25 + t] = a;
    }
}

// ---------------------------------------------------------------------------
// gather: one block per (b,s)
// ---------------------------------------------------------------------------
__global__ __launch_bounds__(64) void gather_kernel(
    const float* __restrict__ comb, const int* __restrict__ rk, float* __restrict__ out)
{
    const int bs = blockIdx.x;
    const int b  = bs >> 8;
    const int t  = threadIdx.x;
    const int r  = rk[bs];
    float* o = out + (size_t)bs * (2 * DD);
    if (r < 0) {
        for (int d = t; d < 2 * DD; d += 64) o[d] = 0.f;
    } else {
        const float* src = comb + (size_t)(b * EE + r) * (2 * DD);
        for (int d = t; d < 2 * DD; d += 64) o[d] = src[d];
    }
}

extern "C" void kernel_launch(void* const* d_in, const int* in_sizes, int n_in,
                              void* d_out, int out_size, void* d_ws, size_t ws_size,
                              hipStream_t stream)
{
    const int*   ent = (const int*)d_in[0];
    const float* q   = (const float*)d_in[1];
    const float* k1  = (const float*)d_in[2];
    const float* v1  = (const float*)d_in[3];
    const float* k2  = (const float*)d_in[4];
    const float* v2  = (const float*)d_in[5];
    const float* Wq2 = (const float*)d_in[6];
    const float* bq2 = (const float*)d_in[7];
    const float* Wk2 = (const float*)d_in[8];
    const float* Wq1 = (const float*)d_in[9];
    const float* bq1 = (const float*)d_in[10];
    const float* Wk1 = (const float*)d_in[11];
    float* out = (float*)d_out;

    float* ws   = (float*)d_ws;
    float* qk2  = ws;                          // [0, 1024)
    float* qk1  = ws + 1024;                   // [1024, 2048)
    int*   rk   = (int*)(ws + 2048);           // [2048, 4096) as ints
    float* comb = ws + 4096;                   // [4096, 4096+409600)
    float* c2   = ws + 4096 + 409600;          // per-b chunks of 409600 floats

    const size_t fixed = 4096 + 409600;        // floats
    const size_t perb  = (size_t)EE * NN1 * DD; // 409600 floats per batch
    size_t wsf = ws_size / sizeof(float);
    int kb = (wsf > fixed) ? (int)((wsf - fixed) / perb) : 1;
    if (kb < 1) kb = 1;
    if (kb > BB) kb = BB;

    prep_kernel<<<24, 256, 0, stream>>>(q, ent, Wq2, bq2, Wk2, Wq1, bq1, Wk1, qk2, qk1, rk);
    for (int b0 = 0; b0 < BB; b0 += kb) {
        const int nb = (BB - b0 < kb) ? (BB - b0) : kb;
        const int nunits = nb * EE * NN1;      // multiple of 64
        const int grid = nunits / 64;          // 64 contiguous units per block
        dk2_kernel<<<grid, 64, 0, stream>>>(k2, v2, qk2, c2, b0, nunits);
        dk1_kernel<<<nb * EE * 2, 64, 0, stream>>>(k1, v1, c2, qk1, comb, b0);
    }
    gather_kernel<<<BB * SS, 64, 0, stream>>>(comb, rk, out);
}